// Round 8
// baseline (984.716 us; speedup 1.0000x reference)
//
#include <hip/hip_runtime.h>
#include <hip/hip_bf16.h>
#include <cstdint>

#define DEVINL __device__ __forceinline__

typedef unsigned short u16;
typedef short bf16x8 __attribute__((ext_vector_type(8)));
typedef float f32x4 __attribute__((ext_vector_type(4)));

// ---------- small helpers ----------
DEVINL u16 f2b(float f) {
    union { float f; uint32_t u; } x{f};
    uint32_t r = x.u + 0x7fffu + ((x.u >> 16) & 1u);   // RNE
    return (u16)(r >> 16);
}
DEVINL float b2f(u16 h) {
    union { uint32_t u; float f; } x{(uint32_t)h << 16};
    return x.f;
}
DEVINL float gelu_exact(float v) {
    return 0.5f * v * (1.0f + erff(v * 0.70710678118654752f));
}
// global -> LDS async DMA, 16B per lane. LDS dest must be wave-uniform base + lane*16.
DEVINL void gload_lds16(const void* g, void* l) {
    __builtin_amdgcn_global_load_lds(
        (const __attribute__((address_space(1))) void*)(uintptr_t)g,
        (__attribute__((address_space(3))) void*)(uint32_t)(uintptr_t)l,
        16, 0, 0);
}

// ---------- fp32 -> bf16 convert ----------
__global__ void f2b_kernel(const float* __restrict__ in, u16* __restrict__ out, int n) {
    int i = (blockIdx.x * 256 + threadIdx.x) * 8;
    if (i + 8 <= n) {
        float4 a = *(const float4*)(in + i);
        float4 b = *(const float4*)(in + i + 4);
        u16 t[8] = {f2b(a.x), f2b(a.y), f2b(a.z), f2b(a.w),
                    f2b(b.x), f2b(b.y), f2b(b.z), f2b(b.w)};
        *(uint4*)(out + i) = *(const uint4*)t;
    }
}

// ---------- pack qkv biases into [3][1536] ----------
__global__ void packb_kernel(const float* __restrict__ bq, const float* __restrict__ bk,
                             const float* __restrict__ bv, float* __restrict__ out) {
    int idx = blockIdx.x * 256 + threadIdx.x;
    if (idx >= 3 * 1536) return;
    int i = idx / 1536, j = idx - i * 1536;
    float v = (j < 512) ? bq[i * 512 + j]
            : (j < 1024) ? bk[i * 512 + j - 512]
                         : bv[i * 512 + j - 1024];
    out[idx] = v;
}

// ---------- positional-embedding table [512][512] ----------
__global__ void pe_kernel(float* __restrict__ pet) {
    int l = blockIdx.x, d2 = threadIdx.x;   // 256 threads: d2 = d>>1
    float freq = expf(-(float)(2 * d2) * 0.0179889460390f); // ln(1e4)/512
    float ang = (float)l * freq;
    pet[l * 512 + 2 * d2]     = sinf(ang);
    pet[l * 512 + 2 * d2 + 1] = cosf(ang);
}

// ---------- per-(b,c) mean/std over L ----------
__global__ void stats_kernel(const float* __restrict__ xe, float* __restrict__ mean,
                             float* __restrict__ stdv) {
    int b = blockIdx.x, ln = threadIdx.x;          // 64 threads
    int c = ln & 15, part = ln >> 4;
    float s = 0.f, sq = 0.f;
    for (int l = part; l < 512; l += 4) {
        float x = xe[(size_t)b * 8192 + l * 16 + c];
        s += x; sq += x * x;
    }
    s += __shfl_xor(s, 16);  s += __shfl_xor(s, 32);
    sq += __shfl_xor(sq, 16); sq += __shfl_xor(sq, 32);
    if (part == 0) {
        float m = s * (1.0f / 512.0f);
        mean[b * 16 + c] = m;
        stdv[b * 16 + c] = sqrtf(sq * (1.0f / 512.0f) - m * m + 1e-5f);
    }
}

// ---------- projector: circ conv over C axis + 3-layer MLP ----------
__global__ __launch_bounds__(128)
void proj_kernel(const float* __restrict__ xe, const float* __restrict__ stats,
                 const float* __restrict__ cw, const float* __restrict__ w0,
                 const float* __restrict__ b0, const float* __restrict__ w1,
                 const float* __restrict__ b1, const float* __restrict__ w2,
                 float* __restrict__ outp, int outn, int do_exp) {
    __shared__ float zl[32], h0l[128], h1l[128], red[2];
    int b = blockIdx.x, tid = threadIdx.x;
    {   // y[c] = sum_{l,t} x[b,l,(c-1+t)%16] * cw[l,t]
        int c = tid >> 3, part = tid & 7;
        float acc = 0.f;
        for (int l = part; l < 512; l += 8) {
            const float* xr = xe + (size_t)b * 8192 + l * 16;
            float w0v = cw[l * 3 + 0], w1v = cw[l * 3 + 1], w2v = cw[l * 3 + 2];
            acc += xr[(c + 15) & 15] * w0v + xr[c] * w1v + xr[(c + 1) & 15] * w2v;
        }
        acc += __shfl_xor(acc, 1); acc += __shfl_xor(acc, 2); acc += __shfl_xor(acc, 4);
        if (part == 0) zl[c] = acc;
        if (tid < 16) zl[16 + tid] = stats[b * 16 + tid];
    }
    __syncthreads();
    {
        float acc = b0[tid];
        #pragma unroll
        for (int i = 0; i < 32; ++i) acc += zl[i] * w0[tid * 32 + i];
        h0l[tid] = fmaxf(acc, 0.0f);
    }
    __syncthreads();
    {
        float acc = b1[tid];
        for (int i = 0; i < 128; ++i) acc += h0l[i] * w1[tid * 128 + i];
        h1l[tid] = fmaxf(acc, 0.0f);
    }
    __syncthreads();
    if (outn == 1) {
        float p = h1l[tid] * w2[tid];
        p += __shfl_xor(p, 1);  p += __shfl_xor(p, 2);  p += __shfl_xor(p, 4);
        p += __shfl_xor(p, 8);  p += __shfl_xor(p, 16); p += __shfl_xor(p, 32);
        if ((tid & 63) == 0) red[tid >> 6] = p;
        __syncthreads();
        if (tid == 0) {
            float v = red[0] + red[1];
            outp[b] = do_exp ? expf(v) : v;
        }
    } else {
        for (int l = tid; l < outn; l += 128) {
            float acc = 0.f;
            for (int i = 0; i < 128; ++i) acc += h1l[i] * w2[l * 128 + i];
            outp[(size_t)b * outn + l] = acc;
        }
    }
}

// ---------- token embedding: circular conv over L + positional embedding ----------
__global__ __launch_bounds__(256)
void tokconv_kernel(const float* __restrict__ xe, const float* __restrict__ tw,
                    const float* __restrict__ pet,
                    float* __restrict__ xf, u16* __restrict__ xb) {
    __shared__ float xs[34][16];
    int lt = blockIdx.x, b = blockIdx.y, tid = threadIdx.x;
    int l0 = lt * 32;
    for (int idx = tid; idx < 34 * 16; idx += 256) {
        int r = idx >> 4, c = idx & 15;
        int gl = (l0 - 1 + r + 512) & 511;
        xs[r][c] = xe[(size_t)b * 8192 + gl * 16 + c];
    }
    __syncthreads();
    for (int dd = tid; dd < 512; dd += 256) {
        float twr[48];
        #pragma unroll
        for (int i = 0; i < 48; ++i) twr[i] = tw[dd * 48 + i];
        for (int l = 0; l < 32; ++l) {
            float acc = 0.f;
            #pragma unroll
            for (int c = 0; c < 16; ++c) {
                acc += xs[l][c]     * twr[c * 3 + 0];
                acc += xs[l + 1][c] * twr[c * 3 + 1];
                acc += xs[l + 2][c] * twr[c * 3 + 2];
            }
            float vv = acc + pet[(size_t)(l0 + l) * 512 + dd];
            size_t idx = ((size_t)b * 512 + l0 + l) * 512 + dd;
            xf[idx] = vv;
            xb[idx] = f2b(vv);
        }
    }
}

// ---------- 256x256 8-phase bf16 GEMM (T1+T3+T4+T5): C = A B^T + bias ----------
// m201-template-faithful: NO sched_barrier in phase body (m141: order-pinning
// costs ~40%), bare counted vmcnt (no "memory" clobber; ds_reads are fenced by
// the raw s_barrier), explicit lgkmcnt(0) before the MFMA cluster.
// Stage schedule: p0-1 buf1A<-kt(2t+1) [hot, used p4], p2-3 buf0B<-kt(2t+2),
// p4-5 buf0A<-kt(2t+2), p6-7 buf1B<-kt(2t+3). vmcnt(4) at p3/p7 only.
template <int ACT>   // 0 none, 1 gelu; bf16 output
__global__ __launch_bounds__(512)
void gemm8p(const u16* __restrict__ A, const u16* __restrict__ B,
            const float* __restrict__ bias, u16* __restrict__ C,
            int M, int N, int K) {
    __shared__ u16 Al[2][256 * 64];   // 64KB
    __shared__ u16 Bl[2][256 * 64];   // 64KB
    const int tid = threadIdx.x, wv = tid >> 6, ln = tid & 63;
    const int lo = ln & 15, hi = ln >> 4;
    const int gx = gridDim.x;
    const int nwg = gx * gridDim.y;
    const int bid = blockIdx.y * gx + blockIdx.x;
    const int wg  = (bid & 7) * (nwg >> 3) + (bid >> 3);   // XCD chunking
    const int n0 = (wg % gx) * 256;
    const int m0 = (wg / gx) * 256;
    const int wm0 = (wv >> 2) * 128, wn0 = (wv & 3) * 64;
    const int srow = wv * 8 + (ln >> 3);   // staging row within half
    const int ssl = ln & 7;                // staging slot (16B units)

    f32x4 acc[8][4] = {};
    bf16x8 bfr[2][4];

    auto stageA = [&](int buf, int half, int kt) {
        #pragma unroll
        for (int c = 0; c < 2; ++c) {
            int row = half * 128 + srow + c * 64;
            gload_lds16(A + (size_t)(m0 + row) * K + kt + (ssl ^ (row & 7)) * 8,
                        (char*)Al[buf] + row * 128 + ssl * 16);
        }
    };
    auto stageB = [&](int buf, int half, int kt) {
        #pragma unroll
        for (int c = 0; c < 2; ++c) {
            int row = half * 128 + srow + c * 64;
            gload_lds16(B + (size_t)(n0 + row) * K + kt + (ssl ^ (row & 7)) * 8,
                        (char*)Bl[buf] + row * 128 + ssl * 16);
        }
    };

    // prologue: ktile0 A+B -> buf0; ktile1 B -> buf1 (A1 is hot-staged at p0-1)
    stageA(0, 0, 0); stageA(0, 1, 0);
    stageB(0, 0, 0); stageB(0, 1, 0);
    stageB(1, 0, 64); stageB(1, 1, 64);
    asm volatile("s_waitcnt vmcnt(4)");   // A0+B0 landed; B1 in flight
    __builtin_amdgcn_s_barrier();

    const int NT2 = K >> 7;   // K-tile pairs
    for (int t = 0; t < NT2; ++t) {
        const bool full = (t < NT2 - 1);
        const int ktA1 = (2 * t + 1) * 64;
        const int ktN  = (2 * t + 2) * 64;
        const int ktB1 = (2 * t + 3) * 64;
        #pragma unroll
        for (int p = 0; p < 8; ++p) {
            const int b = p >> 2, q = p & 3;
            if (q == 0) {   // B fragments for this buffer (reused 4 phases)
                #pragma unroll
                for (int kk = 0; kk < 2; ++kk)
                    #pragma unroll
                    for (int j = 0; j < 4; ++j) {
                        int row = wn0 + j * 16 + lo;
                        bfr[kk][j] = *(const bf16x8*)((const char*)Bl[b] + row * 128 +
                                                      (((kk * 4 + hi) ^ (row & 7)) * 16));
                    }
            }
            bf16x8 af[2][2];
            #pragma unroll
            for (int kk = 0; kk < 2; ++kk)
                #pragma unroll
                for (int c = 0; c < 2; ++c) {
                    int row = wm0 + (q * 2 + c) * 16 + lo;
                    af[kk][c] = *(const bf16x8*)((const char*)Al[b] + row * 128 +
                                                 (((kk * 4 + hi) ^ (row & 7)) * 16));
                }
            switch (p) {   // stage issue (p compile-time constant in unrolled loop)
                case 0: stageA(1, 0, ktA1); break;
                case 1: stageA(1, 1, ktA1); break;
                case 2: if (full) stageB(0, 0, ktN); break;
                case 3: if (full) stageB(0, 1, ktN); break;
                case 4: if (full) stageA(0, 0, ktN); break;
                case 5: if (full) stageA(0, 1, ktN); break;
                case 6: if (full) stageB(1, 0, ktB1); break;
                case 7: if (full) stageB(1, 1, ktB1); break;
            }
            __builtin_amdgcn_s_barrier();
            asm volatile("s_waitcnt lgkmcnt(0)");
            __builtin_amdgcn_s_setprio(1);
            #pragma unroll
            for (int kk = 0; kk < 2; ++kk)
                #pragma unroll
                for (int c = 0; c < 2; ++c)
                    #pragma unroll
                    for (int j = 0; j < 4; ++j)
                        acc[q * 2 + c][j] = __builtin_amdgcn_mfma_f32_16x16x32_bf16(
                            af[kk][c], bfr[kk][j], acc[q * 2 + c][j], 0, 0, 0);
            __builtin_amdgcn_s_setprio(0);
            if (p == 3 || p == 7) {
                if (full) { asm volatile("s_waitcnt vmcnt(4)"); }
                else      { asm volatile("s_waitcnt vmcnt(0)"); }
            }
            __builtin_amdgcn_s_barrier();
        }
    }

    // ---- epilogue: per-wave LDS transpose (LDS drained), coalesced bf16 stores ----
    float* ep = (float*)&Al[0][0] + wv * (16 * 68);
    #pragma unroll
    for (int i = 0; i < 8; ++i) {
        #pragma unroll
        for (int j = 0; j < 4; ++j) {
            int col = n0 + wn0 + j * 16 + lo;
            float bv = bias[col];
            #pragma unroll
            for (int r = 0; r < 4; ++r) {
                float v = acc[i][j][r] + bv;
                if (ACT == 1) v = gelu_exact(v);
                ep[(hi * 4 + r) * 68 + j * 16 + lo] = v;
            }
        }
        #pragma unroll
        for (int pp = 0; pp < 4; ++pp) {
            int rl = pp * 4 + hi;
            float4 vv = *(const float4*)(ep + rl * 68 + lo * 4);
            size_t row = (size_t)(m0 + wm0 + i * 16 + rl);
            int col = n0 + wn0 + lo * 4;
            u16 t4[4] = {f2b(vv.x), f2b(vv.y), f2b(vv.z), f2b(vv.w)};
            *(uint2*)(C + row * N + col) = *(const uint2*)t4;
        }
    }
}

// ---------- bf16 MFMA GEMM (128x128, ring + counted vmcnt + XCD swizzle) ----------
// Used for Oproj / FFN2 (N=512). blockIdx.z = split-K chunk.
template <int ACT, int OBF>
__global__ __launch_bounds__(256)
void gemm_bt(const u16* __restrict__ A, const u16* __restrict__ B,
             const float* __restrict__ bias, void* __restrict__ Cv0,
             u16* __restrict__ Cv1, int M, int N, int K, int Kc) {
    __shared__ u16 smem[3][2][128 * 32];   // 48 KiB: 3-deep ring of [A|B] K-tiles
    const int tid = threadIdx.x, wv = tid >> 6, ln = tid & 63;
    const int nwg = gridDim.x * gridDim.y;
    const int bid = blockIdx.y * gridDim.x + blockIdx.x;
    const int wg  = (bid & 7) * (nwg >> 3) + (bid >> 3);
    const int n0 = (wg % gridDim.x) * 128;
    const int m0 = (wg / gridDim.x) * 128;
    const int kz = blockIdx.z;
    const int wm = (wv >> 1) * 64, wn = (wv & 1) * 64;
    const int lo = ln & 15, hi = ln >> 4;
    f32x4 acc[4][4] = {};
    const int r0 = wv * 16 + (ln >> 2);
    const int sl = ln & 3;
    const int k0 = kz * Kc;

    auto stage = [&](int buf, int kt) {
        #pragma unroll
        for (int c = 0; c < 2; ++c) {
            int row = r0 + c * 64;
            int ssl = sl ^ ((row >> 1) & 3);
            int ldsoff = row * 32 + sl * 8;
            gload_lds16(A + (size_t)(m0 + row) * K + kt + ssl * 8, (char*)smem[buf][0] + ldsoff * 2);
            gload_lds16(B + (size_t)(n0 + row) * K + kt + ssl * 8, (char*)smem[buf][1] + ldsoff * 2);
        }
    };

    const int nt = Kc >> 5;
    stage(0, k0);
    if (nt > 1) stage(1, k0 + 32);
    for (int t = 0; t < nt; ++t) {
        if (t + 1 < nt) { asm volatile("s_waitcnt vmcnt(4)"); }
        else            { asm volatile("s_waitcnt vmcnt(0)"); }
        __builtin_amdgcn_s_barrier();
        if (t + 2 < nt) stage((t + 2) % 3, k0 + (t + 2) * 32);
        const u16* As = smem[t % 3][0];
        const u16* Bs = smem[t % 3][1];
        bf16x8 af[4], bfr[4];
        #pragma unroll
        for (int i = 0; i < 4; ++i) {
            int row = wm + i * 16 + lo;
            int slot = hi ^ ((row >> 1) & 3);
            af[i] = *(const bf16x8*)(As + row * 32 + slot * 8);
        }
        #pragma unroll
        for (int j = 0; j < 4; ++j) {
            int row = wn + j * 16 + lo;
            int slot = hi ^ ((row >> 1) & 3);
            bfr[j] = *(const bf16x8*)(Bs + row * 32 + slot * 8);
        }
        #pragma unroll
        for (int i = 0; i < 4; ++i)
            #pragma unroll
            for (int j = 0; j < 4; ++j)
                acc[i][j] = __builtin_amdgcn_mfma_f32_16x16x32_bf16(af[i], bfr[j], acc[i][j], 0, 0, 0);
    }
    __syncthreads();

    const bool second = (kz != 0);
    float* ep = (float*)smem + wv * (16 * 68);
    #pragma unroll
    for (int i = 0; i < 4; ++i) {
        #pragma unroll
        for (int j = 0; j < 4; ++j) {
            int col = n0 + wn + j * 16 + lo;
            float bv = second ? 0.0f : bias[col];
            #pragma unroll
            for (int r = 0; r < 4; ++r) {
                float v = acc[i][j][r] + bv;
                if (ACT == 1 && !second) v = gelu_exact(v);
                ep[(hi * 4 + r) * 68 + j * 16 + lo] = v;
            }
        }
        #pragma unroll
        for (int pp = 0; pp < 4; ++pp) {
            int rl = pp * 4 + hi;
            float4 vv = *(const float4*)(ep + rl * 68 + lo * 4);
            size_t row = (size_t)(m0 + wm + i * 16 + rl);
            int col = n0 + wn + lo * 4;
            if (second) {
                u16 t4[4] = {f2b(vv.x), f2b(vv.y), f2b(vv.z), f2b(vv.w)};
                *(uint2*)(Cv1 + row * N + col) = *(const uint2*)t4;
            } else if (OBF) {
                u16 t4[4] = {f2b(vv.x), f2b(vv.y), f2b(vv.z), f2b(vv.w)};
                *(uint2*)((u16*)Cv0 + row * N + col) = *(const uint2*)t4;
            } else {
                *(float4*)((float*)Cv0 + row * N + col) = vv;
            }
        }
    }
}

// ---------- attention v2: flash-style, swapped-operand MFMA ----------
__global__ __launch_bounds__(512)
void attn2_kernel(const u16* __restrict__ qkv, const float* __restrict__ tau,
                  const float* __restrict__ delta, u16* __restrict__ o) {
    __shared__ u16 KL[64 * 64];
    __shared__ u16 VT[64 * 72];
    __shared__ u16 PL[8][32 * 64];
    const int tid = threadIdx.x, w = tid >> 6, ln = tid & 63;
    const int lo = ln & 15, hi = ln >> 4;
    const int qh = blockIdx.x, h = blockIdx.y, b = blockIdx.z;
    const size_t qrow0 = (size_t)b * 512;
    const u16* qp = qkv;
    const u16* kp = qkv + 512;
    const u16* vp = qkv + 1024;
    const int hofs = h * 64;
    const float ts = tau[b] * 0.125f;
    u16* Pw = (u16*)PL[w];
    const int q0 = qh * 256 + w * 32;

    bf16x8 qa[2][2];
    #pragma unroll
    for (int i = 0; i < 2; ++i)
        #pragma unroll
        for (int ks = 0; ks < 2; ++ks)
            qa[i][ks] = *(const bf16x8*)(qp + (qrow0 + q0 + i * 16 + lo) * 1536 + hofs + ks * 32 + hi * 8);

    float m_run[2] = {-1e30f, -1e30f};
    float l_run[2] = {0.f, 0.f};
    f32x4 oacc[2][4] = {};

    const int vsl = tid & 7, vsr = tid >> 3;
    uint4 vreg = *(const uint4*)(vp + (qrow0 + vsr) * 1536 + hofs + vsl * 8);

    for (int nt = 0; nt < 8; ++nt) {
        __syncthreads();
        {
            int s = tid >> 3, j = tid & 7;
            int jl = j ^ (s & 7);
            gload_lds16(kp + (qrow0 + nt * 64 + s) * 1536 + hofs + jl * 8,
                        (char*)KL + tid * 16);
        }
        {
            u16 tmp[8]; *(uint4*)tmp = vreg;
            #pragma unroll
            for (int e = 0; e < 8; ++e) {
                int d = vsl * 8 + e;
                int byt = d * 144 + (((vsr >> 3) ^ vsl) << 4) + (vsr & 7) * 2;
                *(u16*)((char*)VT + byt) = tmp[e];
            }
        }
        if (nt < 7)
            vreg = *(const uint4*)(vp + (qrow0 + (nt + 1) * 64 + vsr) * 1536 + hofs + vsl * 8);
        __syncthreads();

        f32x4 sacc[2][4] = {};
        #pragma unroll
        for (int ks = 0; ks < 2; ++ks) {
            #pragma unroll
            for (int jn = 0; jn < 4; ++jn) {
                int s = jn * 16 + lo;
                int phys = (ks * 4 + hi) ^ (s & 7);
                bf16x8 kb = *(const bf16x8*)((const char*)KL + s * 128 + phys * 16);
                #pragma unroll
                for (int i = 0; i < 2; ++i)
                    sacc[i][jn] = __builtin_amdgcn_mfma_f32_16x16x32_bf16(kb, qa[i][ks], sacc[i][jn], 0, 0, 0);
            }
        }
        float tmax[2] = {-1e30f, -1e30f};
        #pragma unroll
        for (int jn = 0; jn < 4; ++jn) {
            float4 dv4 = *(const float4*)(delta + b * 512 + nt * 64 + jn * 16 + hi * 4);
            float dv[4] = {dv4.x, dv4.y, dv4.z, dv4.w};
            #pragma unroll
            for (int i = 0; i < 2; ++i)
                #pragma unroll
                for (int r = 0; r < 4; ++r) {
                    float v = sacc[i][jn][r] * ts + dv[r] * 0.125f;
                    sacc[i][jn][r] = v;
                    tmax[i] = fmaxf(tmax[i], v);
                }
        }
        #pragma unroll
        for (int i = 0; i < 2; ++i) {
            tmax[i] = fmaxf(tmax[i], __shfl_xor(tmax[i], 16));
            tmax[i] = fmaxf(tmax[i], __shfl_xor(tmax[i], 32));
            float mnew = fmaxf(m_run[i], tmax[i]);
            float fac = __expf(m_run[i] - mnew);
            m_run[i] = mnew;
            l_run[i] *= fac;
            #pragma unroll
            for (int jd = 0; jd < 4; ++jd)
                #pragma unroll
                for (int r = 0; r < 4; ++r) oacc[i][jd][r] *= fac;
        }
        #pragma unroll
        for (int i = 0; i < 2; ++i) {
            float ls = 0.f;
            #pragma unroll
            for (int jn = 0; jn < 4; ++jn) {
                float p0 = __expf(sacc[i][jn][0] - m_run[i]);
                float p1 = __expf(sacc[i][jn][1] - m_run[i]);
                float p2 = __expf(sacc[i][jn][2] - m_run[i]);
                float p3 = __expf(sacc[i][jn][3] - m_run[i]);
                ls += (p0 + p1) + (p2 + p3);
                uint2 pk;
                pk.x = (uint32_t)f2b(p0) | ((uint32_t)f2b(p1) << 16);
                pk.y = (uint32_t)f2b(p2) | ((uint32_t)f2b(p3) << 16);
                int q = i * 16 + lo;
                int ls16 = jn * 2 + (hi >> 1);
                int byt = q * 128 + (((ls16 ^ (q & 7)) << 4)) + (hi & 1) * 8;
                *(uint2*)((char*)Pw + byt) = pk;
            }
            ls += __shfl_xor(ls, 16);
            ls += __shfl_xor(ls, 32);
            l_run[i] += ls;
        }
        #pragma unroll
        for (int ks2 = 0; ks2 < 2; ++ks2) {
            bf16x8 pa[2];
            #pragma unroll
            for (int i = 0; i < 2; ++i) {
                int q = i * 16 + lo;
                int phys = (ks2 * 4 + hi) ^ (q & 7);
                pa[i] = *(const bf16x8*)((const char*)Pw + q * 128 + phys * 16);
            }
            #pragma unroll
            for (int jd = 0; jd < 4; ++jd) {
                int d = jd * 16 + lo;
                int cs = (ks2 * 4 + hi) ^ ((d >> 3) & 7);
                bf16x8 vb = *(const bf16x8*)((const char*)VT + d * 144 + cs * 16);
                #pragma unroll
                for (int i = 0; i < 2; ++i)
                    oacc[i][jd] = __builtin_amdgcn_mfma_f32_16x16x32_bf16(vb, pa[i], oacc[i][jd], 0, 0, 0);
            }
        }
    }
    #pragma unroll
    for (int i = 0; i < 2; ++i) {
        float inv = 1.0f / l_run[i];
        #pragma unroll
        for (int jd = 0; jd < 4; ++jd) {
            u16 t4[4];
            #pragma unroll
            for (int r = 0; r < 4; ++r) t4[r] = f2b(oacc[i][jd][r] * inv);
            size_t row = qrow0 + q0 + i * 16 + lo;
            *(uint2*)(o + row * 512 + hofs + jd * 16 + hi * 4) = *(const uint2*)t4;
        }
    }
}

// ---------- layernorm with 2 residuals: x = LN(x + res0 + res1bf); fp32 + bf16 out ----------
__global__ __launch_bounds__(256)
void ln3_kernel(const float* __restrict__ xin, const float* __restrict__ res0,
                const u16* res1, const float* __restrict__ g,
                const float* __restrict__ bta,
                float* __restrict__ xout, u16* xbf) {
    const int row = blockIdx.x * 4 + (threadIdx.x >> 6);
    const int ln = threadIdx.x & 63;
    const float* xr = xin + (size_t)row * 512;
    const float* rr = res0 + (size_t)row * 512;
    const u16* pr = res1 + (size_t)row * 512;
    float4 a = *(const float4*)(xr + ln * 4);
    float4 c = *(const float4*)(xr + 256 + ln * 4);
    float4 ra = *(const float4*)(rr + ln * 4);
    float4 rc = *(const float4*)(rr + 256 + ln * 4);
    uint2 pa_ = *(const uint2*)(pr + ln * 4);
    uint2 pc_ = *(const uint2*)(pr + 256 + ln * 4);
    const u16* pa16 = (const u16*)&pa_;
    const u16* pc16 = (const u16*)&pc_;
    a.x += ra.x + b2f(pa16[0]); a.y += ra.y + b2f(pa16[1]);
    a.z += ra.z + b2f(pa16[2]); a.w += ra.w + b2f(pa16[3]);
    c.x += rc.x + b2f(pc16[0]); c.y += rc.y + b2f(pc16[1]);
    c.z += rc.z + b2f(pc16[2]); c.w += rc.w + b2f(pc16[3]);
    float s = a.x + a.y + a.z + a.w + c.x + c.y + c.z + c.w;
    float sq = a.x*a.x + a.y*a.y + a.z*a.z + a.w*a.w + c.x*c.x + c.y*c.y + c.z*c.z + c.w*c.w;
    #pragma unroll
    for (int m = 1; m < 64; m <<= 1) { s += __shfl_xor(s, m); sq += __shfl_xor(sq, m); }
    float mean = s * 0.001953125f;
    float var = sq * 0.001953125f - mean * mean;
    float rstd = rsqrtf(var + 1e-5f);
    float4 g0 = *(const float4*)(g + ln * 4);
    float4 g1 = *(const float4*)(g + 256 + ln * 4);
    float4 b0 = *(const float4*)(bta + ln * 4);
    float4 b1 = *(const float4*)(bta + 256 + ln * 4);
    float4 o0, o1;
    o0.x = (a.x - mean) * rstd * g0.x + b0.x;
    o0.y = (a.y - mean) * rstd * g0.y + b0.y;
    o0.z = (a.z - mean) * rstd * g0.z + b0.z;
    o0.w = (a.w - mean) * rstd * g0.w + b0.w;
    o1.x = (c.x - mean) * rstd * g1.x + b1.x;
    o1.y = (c.y - mean) * rstd * g1.y + b1.y;
    o1.z = (c.z - mean) * rstd * g1.z + b1.z;
    o1.w = (c.w - mean) * rstd * g1.w + b1.w;
    *(float4*)(xout + (size_t)row * 512 + ln * 4) = o0;
    *(float4*)(xout + (size_t)row * 512 + 256 + ln * 4) = o1;
    u16 t0[4] = {f2b(o0.x), f2b(o0.y), f2b(o0.z), f2b(o0.w)};
    u16 t1[4] = {f2b(o1.x), f2b(o1.y), f2b(o1.z), f2b(o1.w)};
    *(uint2*)(xbf + (size_t)row * 512 + ln * 4) = *(const uint2*)t0;
    *(uint2*)(xbf + (size_t)row * 512 + 256 + ln * 4) = *(const uint2*)t1;
}

// ---------- final LN -> gelu -> * mark -> bf16 ----------
__global__ __launch_bounds__(256)
void lngelu_kernel(const float* __restrict__ xin, const float* __restrict__ g,
                   const float* __restrict__ bta, const float* __restrict__ mark,
                   u16* __restrict__ outb) {
    const int row = blockIdx.x * 4 + (threadIdx.x >> 6);
    const int ln = threadIdx.x & 63;
    const float* xr = xin + (size_t)row * 512;
    float4 a = *(const float4*)(xr + ln * 4);
    float4 c = *(const float4*)(xr + 256 + ln * 4);
    float s = a.x + a.y + a.z + a.w + c.x + c.y + c.z + c.w;
    float sq = a.x*a.x + a.y*a.y + a.z*a.z + a.w*a.w + c.x*c.x + c.y*c.y + c.z*c.z + c.w*c.w;
    #pragma unroll
    for (int m = 1; m < 64; m <<= 1) { s += __shfl_xor(s, m); sq += __shfl_xor(sq, m); }
    float mean = s * 0.001953125f;
    float var = sq * 0.001953125f - mean * mean;
    float rstd = rsqrtf(var + 1e-5f);
    float mk = mark[row];
    float4 g0 = *(const float4*)(g + ln * 4);
    float4 g1 = *(const float4*)(g + 256 + ln * 4);
    float4 b0 = *(const float4*)(bta + ln * 4);
    float4 b1 = *(const float4*)(bta + 256 + ln * 4);
    float v0 = gelu_exact((a.x - mean) * rstd * g0.x + b0.x) * mk;
    float v1 = gelu_exact((a.y - mean) * rstd * g0.y + b0.y) * mk;
    float v2 = gelu_exact((a.z - mean) * rstd * g0.z + b0.z) * mk;
    float v3 = gelu_exact((a.w - mean) * rstd * g0.w + b0.w) * mk;
    float v4 = gelu_exact((c.x - mean) * rstd * g1.x + b1.x) * mk;
    float v5 = gelu_exact((c.y - mean) * rstd * g1.y + b1.y) * mk;
    float v6 = gelu_exact((c.z - mean) * rstd * g1.z + b1.z) * mk;
    float v7 = gelu_exact((c.w - mean) * rstd * g1.w + b1.w) * mk;
    u16 t0[4] = {f2b(v0), f2b(v1), f2b(v2), f2b(v3)};
    u16 t1[4] = {f2b(v4), f2b(v5), f2b(v6), f2b(v7)};
    *(uint2*)(outb + (size_t)row * 512 + ln * 4) = *(const uint2*)t0;
    *(uint2*)(outb + (size_t)row * 512 + 256 + ln * 4) = *(const uint2*)t1;
}

// ---------- final projection: out[32,10] = gb[32,262144] @ pw[10,262144]^T + pb ----------
__global__ __launch_bounds__(256)
void fproj_kernel(const u16* __restrict__ gb, const u16* __restrict__ pw,
                  const float* __restrict__ pb, float* __restrict__ out) {
    __shared__ float red[32][4];
    int n = blockIdx.x, ks = blockIdx.y, tid = threadIdx.x;
    float acc[32];
    #pragma unroll
    for (int m = 0; m < 32; ++m) acc[m] = 0.f;
    for (int j = 0; j < 8; ++j) {
        size_t k0 = (size_t)ks * 16384 + j * 2048 + tid * 8;
        bf16x8 w8 = *(const bf16x8*)(pw + (size_t)n * 262144 + k0);
        float wf[8];
        #pragma unroll
        for (int e = 0; e < 8; ++e) wf[e] = b2f((u16)w8[e]);
        #pragma unroll
        for (int m = 0; m < 32; ++m) {
            bf16x8 g8 = *(const bf16x8*)(gb + (size_t)m * 262144 + k0);
            float a = acc[m];
            #pragma unroll
            for (int e = 0; e < 8; ++e) a += b2f((u16)g8[e]) * wf[e];
            acc[m] = a;
        }
    }
    int w = tid >> 6;
    #pragma unroll
    for (int m = 0; m < 32; ++m) {
        float s = acc[m];
        s += __shfl_xor(s, 1);  s += __shfl_xor(s, 2);  s += __shfl_xor(s, 4);
        s += __shfl_xor(s, 8);  s += __shfl_xor(s, 16); s += __shfl_xor(s, 32);
        if ((tid & 63) == 0) red[m][w] = s;
    }
    __syncthreads();
    if (tid < 32) {
        int m = tid;
        float s = red[m][0] + red[m][1] + red[m][2] + red[m][3];
        if (ks == 0) s += pb[n];
        atomicAdd(&out[m * 10 + n], s);
    }
}

// =================== host ===================
extern "C" void kernel_launch(void* const* d_in, const int* in_sizes, int n_in,
                              void* d_out, int out_size, void* d_ws, size_t ws_size,
                              hipStream_t stream) {
    const float* x_enc  = (const float*)d_in[0];
    const float* x_mark = (const float*)d_in[1];
    const float* tok_w  = (const float*)d_in[2];
    const float* Wq = (const float*)d_in[3];   const float* bq = (const float*)d_in[4];
    const float* Wk = (const float*)d_in[5];   const float* bk = (const float*)d_in[6];
    const float* Wv = (const float*)d_in[7];   const float* bv = (const float*)d_in[8];
    const float* Wo = (const float*)d_in[9];   const float* bo = (const float*)d_in[10];
    const float* W1 = (const float*)d_in[11];  const float* b1 = (const float*)d_in[12];
    const float* W2 = (const float*)d_in[13];  const float* b2 = (const float*)d_in[14];
    const float* ln1_g = (const float*)d_in[15]; const float* ln1_b = (const float*)d_in[16];
    const float* ln2_g = (const float*)d_in[17]; const float* ln2_b = (const float*)d_in[18];
    const float* norm_g = (const float*)d_in[19]; const float* norm_b = (const float*)d_in[20];
    const float* proj_w = (const float*)d_in[21]; const float* proj_b = (const float*)d_in[22];
    const float* tau_cw = (const float*)d_in[23];
    const float* tau_w0 = (const float*)d_in[24]; const float* tau_b0 = (const float*)d_in[25];
    const float* tau_w1 = (const float*)d_in[26]; const float* tau_b1 = (const float*)d_in[27];
    const float* tau_w2 = (const float*)d_in[28];
    const float* del_cw = (const float*)d_in[29];
    const float* del_w0 = (const float*)d_in[30]; const float* del_b0 = (const float*)d_in[31];
    const float* del_w1 = (const float*)d_in[32]; const float* del_b1 = (const float*)d_in[33];
    const float* del_w2 = (const float*)d_in[34];
    float* out = (float*)d_out;

    char* ws = (char*)d_ws;
    size_t off = 0;
    auto alloc = [&](size_t bytes) -> void* {
        void* p = ws + off;
        off += (bytes + 255) & ~(size_t)255;
        return p;
    };
    u16* wqkvb = (u16*)alloc((size_t)3 * 786432 * 2);   // per layer [1536][512]
    u16* wob = (u16*)alloc(786432 * 2);
    u16* w1b = (u16*)alloc(3145728 * 2);
    u16* w2b = (u16*)alloc(3145728 * 2);
    u16* pwb = (u16*)alloc(2621440 * 2);
    float* bqkvb = (float*)alloc(3 * 1536 * 4);
    float* petab = (float*)alloc((size_t)262144 * 4);
    float* meanb = (float*)alloc(512 * 4);
    float* stdb  = (float*)alloc(512 * 4);
    float* taub  = (float*)alloc(32 * 4);
    float* delb  = (float*)alloc(16384 * 4);
    float* xf = (float*)alloc((size_t)8388608 * 4);
    u16*  xb  = (u16*)alloc((size_t)8388608 * 2);
    float* sf = (float*)alloc((size_t)8388608 * 4);
    u16* qkvb = (u16*)alloc((size_t)16384 * 1536 * 2);  // 50.3MB
    u16* ob   = (u16*)alloc((size_t)8388608 * 2);       // 16.8MB
    u16* hb   = qkvb;   // FFN hidden (64MB) overlays qkvb AND first 13.7MB of ob
    u16* gbuf = qkvb;   // final gelu buffer overlays too
    u16* p1o  = qkvb;   // Oproj split-K partial: qkvb dead during Oproj/ln1
    u16* p1f  = xb;     // FFN2 split-K partial: xb dead during FFN2 (see R4 postmortem)

    auto cvt = [&](const float* src, u16* dst, int n) {
        f2b_kernel<<<dim3((n + 2047) / 2048), dim3(256), 0, stream>>>(src, dst, n);
    };
    for (int i = 0; i < 3; ++i) {
        cvt(Wq + (size_t)i * 262144, wqkvb + (size_t)i * 786432 + 0,      262144);
        cvt(Wk + (size_t)i * 262144, wqkvb + (size_t)i * 786432 + 262144, 262144);
        cvt(Wv + (size_t)i * 262144, wqkvb + (size_t)i * 786432 + 524288, 262144);
    }
    cvt(Wo, wob, 786432);
    cvt(W1, w1b, 3145728); cvt(W2, w2b, 3145728);
    cvt(proj_w, pwb, 2621440);
    packb_kernel<<<dim3(18), dim3(256), 0, stream>>>(bq, bk, bv, bqkvb);
    pe_kernel<<<dim3(512), dim3(256), 0, stream>>>(petab);

    stats_kernel<<<dim3(32), dim3(64), 0, stream>>>(x_enc, meanb, stdb);
    proj_kernel<<<dim3(32), dim3(128), 0, stream>>>(x_enc, stdb, tau_cw, tau_w0, tau_b0,
                                                    tau_w1, tau_b1, tau_w2, taub, 1, 1);
    proj_kernel<<<dim3(32), dim3(128), 0, stream>>>(x_enc, meanb, del_cw, del_w0, del_b0,
                                                    del_w1, del_b1, del_w2, delb, 512, 0);
    tokconv_kernel<<<dim3(16, 32), dim3(256), 0, stream>>>(x_enc, tok_w, petab, xf, xb);

    for (int i = 0; i < 3; ++i) {
        const u16* wqkv_i = wqkvb + (size_t)i * 786432;
        const u16* wo_i = wob + (size_t)i * 262144;
        const u16* w1_i = w1b + (size_t)i * 1048576;
        const u16* w2_i = w2b + (size_t)i * 1048576;
        gemm8p<0><<<dim3(6, 64), dim3(512), 0, stream>>>(
            xb, wqkv_i, bqkvb + i * 1536, qkvb, 16384, 1536, 512);
        attn2_kernel<<<dim3(2, 8, 32), dim3(512), 0, stream>>>(qkvb, taub, delb, ob);
        gemm_bt<0, 0><<<dim3(4, 128, 2), dim3(256), 0, stream>>>(
            ob, wo_i, bo + i * 512, sf, p1o, 16384, 512, 512, 256);
        ln3_kernel<<<dim3(4096), dim3(256), 0, stream>>>(xf, sf, p1o,
            ln1_g + i * 512, ln1_b + i * 512, xf, xb);
        gemm8p<1><<<dim3(8, 64), dim3(512), 0, stream>>>(
            xb, w1_i, b1 + i * 2048, hb, 16384, 2048, 512);
        gemm_bt<0, 0><<<dim3(4, 128, 2), dim3(256), 0, stream>>>(
            hb, w2_i, b2 + i * 512, sf, p1f, 16384, 512, 2048, 1024);
        ln3_kernel<<<dim3(4096), dim3(256), 0, stream>>>(xf, sf, p1f,
            ln2_g + i * 512, ln2_b + i * 512, xf, xb);
    }

    lngelu_kernel<<<dim3(4096), dim3(256), 0, stream>>>(xf, norm_g, norm_b, x_mark, gbuf);
    hipMemsetAsync(d_out, 0, (size_t)out_size * 4, stream);
    fproj_kernel<<<dim3(10, 16), dim3(256), 0, stream>>>(gbuf, pwb, proj_b, out);
}

// Round 9
// 980.788 us; speedup vs baseline: 1.0040x; 1.0040x over previous
//
#include <hip/hip_runtime.h>
#include <hip/hip_bf16.h>
#include <cstdint>

#define DEVINL __device__ __forceinline__

typedef unsigned short u16;
typedef short bf16x8 __attribute__((ext_vector_type(8)));
typedef float f32x4 __attribute__((ext_vector_type(4)));
typedef float f32x16 __attribute__((ext_vector_type(16)));

// ---------- small helpers ----------
DEVINL u16 f2b(float f) {
    union { float f; uint32_t u; } x{f};
    uint32_t r = x.u + 0x7fffu + ((x.u >> 16) & 1u);   // RNE
    return (u16)(r >> 16);
}
DEVINL float b2f(u16 h) {
    union { uint32_t u; float f; } x{(uint32_t)h << 16};
    return x.f;
}
DEVINL float gelu_exact(float v) {
    return 0.5f * v * (1.0f + erff(v * 0.70710678118654752f));
}
// global -> LDS async DMA, 16B per lane. LDS dest must be wave-uniform base + lane*16.
DEVINL void gload_lds16(const void* g, void* l) {
    __builtin_amdgcn_global_load_lds(
        (const __attribute__((address_space(1))) void*)(uintptr_t)g,
        (__attribute__((address_space(3))) void*)(uint32_t)(uintptr_t)l,
        16, 0, 0);
}
DEVINL void cvt8(const float* src, u16* dst) {
    float4 a = *(const float4*)src;
    float4 b = *(const float4*)(src + 4);
    u16 t[8] = {f2b(a.x), f2b(a.y), f2b(a.z), f2b(a.w),
                f2b(b.x), f2b(b.y), f2b(b.z), f2b(b.w)};
    *(uint4*)dst = *(const uint4*)t;
}

// ---------- batched weight converts (13 dispatches -> 2) ----------
// 9 slices of 262144: Wq/Wk/Wv x 3 layers -> wqkvb [layer][3*262144]
__global__ __launch_bounds__(256)
void cvtqkv_kernel(const float* __restrict__ Wq, const float* __restrict__ Wk,
                   const float* __restrict__ Wv, u16* __restrict__ dst) {
    size_t i = ((size_t)blockIdx.x * 256 + threadIdx.x) * 8;   // total 2359296
    int slice = (int)(i >> 18);           // /262144
    int layer = slice / 3, which = slice - layer * 3;
    size_t rem = i & 262143;
    const float* src = (which == 0 ? Wq : which == 1 ? Wk : Wv) + (size_t)layer * 262144 + rem;
    u16* d = dst + (size_t)layer * 786432 + (size_t)which * 262144 + rem;
    cvt8(src, d);
}
// Wo(786432) + W1(3145728) + W2(3145728) + proj_w(2621440) = 10299520 elements
__global__ __launch_bounds__(256)
void cvt4_kernel(const float* __restrict__ s0, const float* __restrict__ s1,
                 const float* __restrict__ s2, const float* __restrict__ s3,
                 u16* __restrict__ d0, u16* __restrict__ d1,
                 u16* __restrict__ d2, u16* __restrict__ d3) {
    size_t i = ((size_t)blockIdx.x * 256 + threadIdx.x) * 8;
    if (i < 786432) { cvt8(s0 + i, d0 + i); return; }
    i -= 786432;
    if (i < 3145728) { cvt8(s1 + i, d1 + i); return; }
    i -= 3145728;
    if (i < 3145728) { cvt8(s2 + i, d2 + i); return; }
    i -= 3145728;
    if (i < 2621440) { cvt8(s3 + i, d3 + i); }
}

// ---------- pack qkv biases into [3][1536] ----------
__global__ void packb_kernel(const float* __restrict__ bq, const float* __restrict__ bk,
                             const float* __restrict__ bv, float* __restrict__ out) {
    int idx = blockIdx.x * 256 + threadIdx.x;
    if (idx >= 3 * 1536) return;
    int i = idx / 1536, j = idx - i * 1536;
    float v = (j < 512) ? bq[i * 512 + j]
            : (j < 1024) ? bk[i * 512 + j - 512]
                         : bv[i * 512 + j - 1024];
    out[idx] = v;
}

// ---------- positional-embedding table [512][512] ----------
__global__ void pe_kernel(float* __restrict__ pet) {
    int l = blockIdx.x, d2 = threadIdx.x;   // 256 threads: d2 = d>>1
    float freq = expf(-(float)(2 * d2) * 0.0179889460390f); // ln(1e4)/512
    float ang = (float)l * freq;
    pet[l * 512 + 2 * d2]     = sinf(ang);
    pet[l * 512 + 2 * d2 + 1] = cosf(ang);
}

// ---------- per-(b,c) mean/std over L ----------
__global__ void stats_kernel(const float* __restrict__ xe, float* __restrict__ mean,
                             float* __restrict__ stdv) {
    int b = blockIdx.x, ln = threadIdx.x;          // 64 threads
    int c = ln & 15, part = ln >> 4;
    float s = 0.f, sq = 0.f;
    for (int l = part; l < 512; l += 4) {
        float x = xe[(size_t)b * 8192 + l * 16 + c];
        s += x; sq += x * x;
    }
    s += __shfl_xor(s, 16);  s += __shfl_xor(s, 32);
    sq += __shfl_xor(sq, 16); sq += __shfl_xor(sq, 32);
    if (part == 0) {
        float m = s * (1.0f / 512.0f);
        mean[b * 16 + c] = m;
        stdv[b * 16 + c] = sqrtf(sq * (1.0f / 512.0f) - m * m + 1e-5f);
    }
}

// ---------- projector: circ conv over C axis + 3-layer MLP ----------
__global__ __launch_bounds__(128)
void proj_kernel(const float* __restrict__ xe, const float* __restrict__ stats,
                 const float* __restrict__ cw, const float* __restrict__ w0,
                 const float* __restrict__ b0, const float* __restrict__ w1,
                 const float* __restrict__ b1, const float* __restrict__ w2,
                 float* __restrict__ outp, int outn, int do_exp) {
    __shared__ float zl[32], h0l[128], h1l[128], red[2];
    int b = blockIdx.x, tid = threadIdx.x;
    {
        int c = tid >> 3, part = tid & 7;
        float acc = 0.f;
        for (int l = part; l < 512; l += 8) {
            const float* xr = xe + (size_t)b * 8192 + l * 16;
            float w0v = cw[l * 3 + 0], w1v = cw[l * 3 + 1], w2v = cw[l * 3 + 2];
            acc += xr[(c + 15) & 15] * w0v + xr[c] * w1v + xr[(c + 1) & 15] * w2v;
        }
        acc += __shfl_xor(acc, 1); acc += __shfl_xor(acc, 2); acc += __shfl_xor(acc, 4);
        if (part == 0) zl[c] = acc;
        if (tid < 16) zl[16 + tid] = stats[b * 16 + tid];
    }
    __syncthreads();
    {
        float acc = b0[tid];
        #pragma unroll
        for (int i = 0; i < 32; ++i) acc += zl[i] * w0[tid * 32 + i];
        h0l[tid] = fmaxf(acc, 0.0f);
    }
    __syncthreads();
    {
        float acc = b1[tid];
        for (int i = 0; i < 128; ++i) acc += h0l[i] * w1[tid * 128 + i];
        h1l[tid] = fmaxf(acc, 0.0f);
    }
    __syncthreads();
    if (outn == 1) {
        float p = h1l[tid] * w2[tid];
        p += __shfl_xor(p, 1);  p += __shfl_xor(p, 2);  p += __shfl_xor(p, 4);
        p += __shfl_xor(p, 8);  p += __shfl_xor(p, 16); p += __shfl_xor(p, 32);
        if ((tid & 63) == 0) red[tid >> 6] = p;
        __syncthreads();
        if (tid == 0) {
            float v = red[0] + red[1];
            outp[b] = do_exp ? expf(v) : v;
        }
    } else {
        for (int l = tid; l < outn; l += 128) {
            float acc = 0.f;
            for (int i = 0; i < 128; ++i) acc += h1l[i] * w2[l * 128 + i];
            outp[(size_t)b * outn + l] = acc;
        }
    }
}

// ---------- token embedding: circular conv over L + positional embedding ----------
__global__ __launch_bounds__(256)
void tokconv_kernel(const float* __restrict__ xe, const float* __restrict__ tw,
                    const float* __restrict__ pet,
                    float* __restrict__ xf, u16* __restrict__ xb) {
    __shared__ float xs[34][16];
    int lt = blockIdx.x, b = blockIdx.y, tid = threadIdx.x;
    int l0 = lt * 32;
    for (int idx = tid; idx < 34 * 16; idx += 256) {
        int r = idx >> 4, c = idx & 15;
        int gl = (l0 - 1 + r + 512) & 511;
        xs[r][c] = xe[(size_t)b * 8192 + gl * 16 + c];
    }
    __syncthreads();
    for (int dd = tid; dd < 512; dd += 256) {
        float twr[48];
        #pragma unroll
        for (int i = 0; i < 48; ++i) twr[i] = tw[dd * 48 + i];
        for (int l = 0; l < 32; ++l) {
            float acc = 0.f;
            #pragma unroll
            for (int c = 0; c < 16; ++c) {
                acc += xs[l][c]     * twr[c * 3 + 0];
                acc += xs[l + 1][c] * twr[c * 3 + 1];
                acc += xs[l + 2][c] * twr[c * 3 + 2];
            }
            float vv = acc + pet[(size_t)(l0 + l) * 512 + dd];
            size_t idx = ((size_t)b * 512 + l0 + l) * 512 + dd;
            xf[idx] = vv;
            xb[idx] = f2b(vv);
        }
    }
}

// ---------- bf16 GEMM via mfma_f32_32x32x16: C[M,N] = A[M,K] B[N,K]^T (+bias) ----------
// 128x128 tile, 4 waves (2x2, each 64x64 via 2x2 32x32 frags), BK=32, ring-3 LDS
// (48KB -> 3 blocks/CU), counted vmcnt, XCD swizzle. Per K-step per wave:
// 8 ds_read_b128 + 8 MFMA (vs 12+16 with 16x16x32) -> ~40% less issue/LDS
// overhead per FLOP. blockIdx.z = split-K chunk; kz>0 -> partial to Cv1.
// Output always bf16. Frag layouts: A/B lane l: row/col=l&31, k=(l>>5)*8+e;
// D: col=l&31, row=4*(l>>5)+(reg&3)+8*(reg>>2)  [m74/m101].
template <int ACT>
__global__ __launch_bounds__(256)
void gemm32(const u16* __restrict__ A, const u16* __restrict__ B,
            const float* __restrict__ bias, u16* __restrict__ Cv0,
            u16* __restrict__ Cv1, int M, int N, int K, int Kc) {
    __shared__ u16 smem[3][2][128 * 32];   // 48 KiB ring of [A|B] K-tiles
    const int tid = threadIdx.x, wv = tid >> 6, ln = tid & 63;
    const int nwg = gridDim.x * gridDim.y;
    const int bid = blockIdx.y * gridDim.x + blockIdx.x;
    const int wg  = (bid & 7) * (nwg >> 3) + (bid >> 3);   // XCD chunking
    const int n0 = (wg % gridDim.x) * 128;
    const int m0 = (wg / gridDim.x) * 128;
    const int kz = blockIdx.z;
    const int wm = (wv >> 1) * 64, wn = (wv & 1) * 64;
    const int l31 = ln & 31, h2 = ln >> 5;
    f32x16 acc[2][2] = {};
    const int r0s = wv * 16 + (ln >> 2);   // staging row
    const int sl = ln & 3;                 // staging slot
    const int k0 = kz * Kc;

    auto stage = [&](int buf, int kt) {
        #pragma unroll
        for (int c = 0; c < 2; ++c) {
            int row = r0s + c * 64;
            int ssl = sl ^ ((row >> 1) & 3);   // pre-swizzled source chunk
            int ldsoff = row * 32 + sl * 8;
            gload_lds16(A + (size_t)(m0 + row) * K + kt + ssl * 8, (char*)smem[buf][0] + ldsoff * 2);
            gload_lds16(B + (size_t)(n0 + row) * K + kt + ssl * 8, (char*)smem[buf][1] + ldsoff * 2);
        }
    };

    const int nt = Kc >> 5;
    stage(0, k0);
    if (nt > 1) stage(1, k0 + 32);
    for (int t = 0; t < nt; ++t) {
        if (t + 1 < nt) { asm volatile("s_waitcnt vmcnt(4)"); }
        else            { asm volatile("s_waitcnt vmcnt(0)"); }
        __builtin_amdgcn_s_barrier();
        if (t + 2 < nt) stage((t + 2) % 3, k0 + (t + 2) * 32);
        const u16* As = smem[t % 3][0];
        const u16* Bs = smem[t % 3][1];
        bf16x8 af[2][2], bfr[2][2];
        #pragma unroll
        for (int mi = 0; mi < 2; ++mi) {
            int row = wm + mi * 32 + l31;
            int swz = (row >> 1) & 3;
            #pragma unroll
            for (int kk = 0; kk < 2; ++kk) {
                int phys = (kk * 2 + h2) ^ swz;
                af[mi][kk] = *(const bf16x8*)(As + row * 32 + phys * 8);
            }
        }
        #pragma unroll
        for (int nj = 0; nj < 2; ++nj) {
            int row = wn + nj * 32 + l31;
            int swz = (row >> 1) & 3;
            #pragma unroll
            for (int kk = 0; kk < 2; ++kk) {
                int phys = (kk * 2 + h2) ^ swz;
                bfr[nj][kk] = *(const bf16x8*)(Bs + row * 32 + phys * 8);
            }
        }
        #pragma unroll
        for (int mi = 0; mi < 2; ++mi)
            #pragma unroll
            for (int nj = 0; nj < 2; ++nj)
                #pragma unroll
                for (int kk = 0; kk < 2; ++kk)
                    acc[mi][nj] = __builtin_amdgcn_mfma_f32_32x32x16_bf16(
                        af[mi][kk], bfr[nj][kk], acc[mi][nj], 0, 0, 0);
    }
    __syncthreads();   // DMA drained (vmcnt(0)), reads done -> smem reusable

    // ---- epilogue: per-wave 16-row-chunk transpose -> coalesced 8B stores ----
    const bool second = (kz != 0);
    float* eps = (float*)smem + wv * (16 * 68);   // 4 x 4352B = 17.4KB of 48KB
    u16* Cout = second ? Cv1 : Cv0;
    #pragma unroll
    for (int ch = 0; ch < 4; ++ch) {
        const int mi = ch >> 1, rsel = ch & 1;
        #pragma unroll
        for (int nj = 0; nj < 2; ++nj) {
            int col = nj * 32 + l31;
            float bv = second ? 0.0f : bias[n0 + wn + col];
            #pragma unroll
            for (int r1l = 0; r1l < 2; ++r1l)
                #pragma unroll
                for (int rr = 0; rr < 4; ++rr) {
                    int reg = rr + 4 * (rsel * 2 + r1l);
                    int rloc = h2 * 4 + rr + 8 * r1l;
                    float v = acc[mi][nj][reg] + bv;
                    if (ACT == 1 && !second) v = gelu_exact(v);
                    eps[rloc * 68 + col] = v;
                }
        }
        #pragma unroll
        for (int pp = 0; pp < 4; ++pp) {
            int rl = pp * 4 + (ln >> 4);
            float4 vv = *(const float4*)(eps + rl * 68 + (ln & 15) * 4);
            size_t row = (size_t)(m0 + wm + ch * 16 + rl);
            int col = n0 + wn + (ln & 15) * 4;
            u16 t4[4] = {f2b(vv.x), f2b(vv.y), f2b(vv.z), f2b(vv.w)};
            *(uint2*)(Cout + row * N + col) = *(const uint2*)t4;
        }
    }
}

// ---------- attention: flash-style, swapped-operand MFMA ----------
__global__ __launch_bounds__(512)
void attn2_kernel(const u16* __restrict__ qkv, const float* __restrict__ tau,
                  const float* __restrict__ delta, u16* __restrict__ o) {
    __shared__ u16 KL[64 * 64];
    __shared__ u16 VT[64 * 72];
    __shared__ u16 PL[8][32 * 64];
    const int tid = threadIdx.x, w = tid >> 6, ln = tid & 63;
    const int lo = ln & 15, hi = ln >> 4;
    const int qh = blockIdx.x, h = blockIdx.y, b = blockIdx.z;
    const size_t qrow0 = (size_t)b * 512;
    const u16* qp = qkv;
    const u16* kp = qkv + 512;
    const u16* vp = qkv + 1024;
    const int hofs = h * 64;
    const float ts = tau[b] * 0.125f;
    u16* Pw = (u16*)PL[w];
    const int q0 = qh * 256 + w * 32;

    bf16x8 qa[2][2];
    #pragma unroll
    for (int i = 0; i < 2; ++i)
        #pragma unroll
        for (int ks = 0; ks < 2; ++ks)
            qa[i][ks] = *(const bf16x8*)(qp + (qrow0 + q0 + i * 16 + lo) * 1536 + hofs + ks * 32 + hi * 8);

    float m_run[2] = {-1e30f, -1e30f};
    float l_run[2] = {0.f, 0.f};
    f32x4 oacc[2][4] = {};

    const int vsl = tid & 7, vsr = tid >> 3;
    uint4 vreg = *(const uint4*)(vp + (qrow0 + vsr) * 1536 + hofs + vsl * 8);

    for (int nt = 0; nt < 8; ++nt) {
        __syncthreads();
        {
            int s = tid >> 3, j = tid & 7;
            int jl = j ^ (s & 7);
            gload_lds16(kp + (qrow0 + nt * 64 + s) * 1536 + hofs + jl * 8,
                        (char*)KL + tid * 16);
        }
        {
            u16 tmp[8]; *(uint4*)tmp = vreg;
            #pragma unroll
            for (int e = 0; e < 8; ++e) {
                int d = vsl * 8 + e;
                int byt = d * 144 + (((vsr >> 3) ^ vsl) << 4) + (vsr & 7) * 2;
                *(u16*)((char*)VT + byt) = tmp[e];
            }
        }
        if (nt < 7)
            vreg = *(const uint4*)(vp + (qrow0 + (nt + 1) * 64 + vsr) * 1536 + hofs + vsl * 8);
        __syncthreads();

        f32x4 sacc[2][4] = {};
        #pragma unroll
        for (int ks = 0; ks < 2; ++ks) {
            #pragma unroll
            for (int jn = 0; jn < 4; ++jn) {
                int s = jn * 16 + lo;
                int phys = (ks * 4 + hi) ^ (s & 7);
                bf16x8 kb = *(const bf16x8*)((const char*)KL + s * 128 + phys * 16);
                #pragma unroll
                for (int i = 0; i < 2; ++i)
                    sacc[i][jn] = __builtin_amdgcn_mfma_f32_16x16x32_bf16(kb, qa[i][ks], sacc[i][jn], 0, 0, 0);
            }
        }
        float tmax[2] = {-1e30f, -1e30f};
        #pragma unroll
        for (int jn = 0; jn < 4; ++jn) {
            float4 dv4 = *(const float4*)(delta + b * 512 + nt * 64 + jn * 16 + hi * 4);
            float dv[4] = {dv4.x, dv4.y, dv4.z, dv4.w};
            #pragma unroll
            for (int i = 0; i < 2; ++i)
                #pragma unroll
                for (int r = 0; r < 4; ++r) {
                    float v = sacc[i][jn][r] * ts + dv[r] * 0.125f;
                    sacc[i][jn][r] = v;
                    tmax[i] = fmaxf(tmax[i], v);
                }
        }
        #pragma unroll
        for (int i = 0; i < 2; ++i) {
            tmax[i] = fmaxf(tmax[i], __shfl_xor(tmax[i], 16));
            tmax[i] = fmaxf(tmax[i], __shfl_xor(tmax[i], 32));
            float mnew = fmaxf(m_run[i], tmax[i]);
            float fac = __expf(m_run[i] - mnew);
            m_run[i] = mnew;
            l_run[i] *= fac;
            #pragma unroll
            for (int jd = 0; jd < 4; ++jd)
                #pragma unroll
                for (int r = 0; r < 4; ++r) oacc[i][jd][r] *= fac;
        }
        #pragma unroll
        for (int i = 0; i < 2; ++i) {
            float ls = 0.f;
            #pragma unroll
            for (int jn = 0; jn < 4; ++jn) {
                float p0 = __expf(sacc[i][jn][0] - m_run[i]);
                float p1 = __expf(sacc[i][jn][1] - m_run[i]);
                float p2 = __expf(sacc[i][jn][2] - m_run[i]);
                float p3 = __expf(sacc[i][jn][3] - m_run[i]);
                ls += (p0 + p1) + (p2 + p3);
                uint2 pk;
                pk.x = (uint32_t)f2b(p0) | ((uint32_t)f2b(p1) << 16);
                pk.y = (uint32_t)f2b(p2) | ((uint32_t)f2b(p3) << 16);
                int q = i * 16 + lo;
                int ls16 = jn * 2 + (hi >> 1);
                int byt = q * 128 + (((ls16 ^ (q & 7)) << 4)) + (hi & 1) * 8;
                *(uint2*)((char*)Pw + byt) = pk;
            }
            ls += __shfl_xor(ls, 16);
            ls += __shfl_xor(ls, 32);
            l_run[i] += ls;
        }
        #pragma unroll
        for (int ks2 = 0; ks2 < 2; ++ks2) {
            bf16x8 pa[2];
            #pragma unroll
            for (int i = 0; i < 2; ++i) {
                int q = i * 16 + lo;
                int phys = (ks2 * 4 + hi) ^ (q & 7);
                pa[i] = *(const bf16x8*)((const char*)Pw + q * 128 + phys * 16);
            }
            #pragma unroll
            for (int jd = 0; jd < 4; ++jd) {
                int d = jd * 16 + lo;
                int cs = (ks2 * 4 + hi) ^ ((d >> 3) & 7);
                bf16x8 vb = *(const bf16x8*)((const char*)VT + d * 144 + cs * 16);
                #pragma unroll
                for (int i = 0; i < 2; ++i)
                    oacc[i][jd] = __builtin_amdgcn_mfma_f32_16x16x32_bf16(vb, pa[i], oacc[i][jd], 0, 0, 0);
            }
        }
    }
    #pragma unroll
    for (int i = 0; i < 2; ++i) {
        float inv = 1.0f / l_run[i];
        #pragma unroll
        for (int jd = 0; jd < 4; ++jd) {
            u16 t4[4];
            #pragma unroll
            for (int r = 0; r < 4; ++r) t4[r] = f2b(oacc[i][jd][r] * inv);
            size_t row = qrow0 + q0 + i * 16 + lo;
            *(uint2*)(o + row * 512 + hofs + jd * 16 + hi * 4) = *(const uint2*)t4;
        }
    }
}

// ---------- layernorm, 2 bf16 residuals: x = LN(xf + r0 + r1); fp32 + bf16 out ----------
// NOTE: res1 may alias xbf (each element read only by the thread that writes it).
__global__ __launch_bounds__(256)
void ln3_kernel(const float* __restrict__ xin, const u16* res0,
                const u16* res1, const float* __restrict__ g,
                const float* __restrict__ bta,
                float* __restrict__ xout, u16* xbf) {
    const int row = blockIdx.x * 4 + (threadIdx.x >> 6);
    const int ln = threadIdx.x & 63;
    const float* xr = xin + (size_t)row * 512;
    const u16* r0p = res0 + (size_t)row * 512;
    const u16* r1p = res1 + (size_t)row * 512;
    float4 a = *(const float4*)(xr + ln * 4);
    float4 c = *(const float4*)(xr + 256 + ln * 4);
    uint2 qa_ = *(const uint2*)(r0p + ln * 4);
    uint2 qc_ = *(const uint2*)(r0p + 256 + ln * 4);
    uint2 pa_ = *(const uint2*)(r1p + ln * 4);
    uint2 pc_ = *(const uint2*)(r1p + 256 + ln * 4);
    const u16* qa16 = (const u16*)&qa_;  const u16* qc16 = (const u16*)&qc_;
    const u16* pa16 = (const u16*)&pa_;  const u16* pc16 = (const u16*)&pc_;
    a.x += b2f(qa16[0]) + b2f(pa16[0]); a.y += b2f(qa16[1]) + b2f(pa16[1]);
    a.z += b2f(qa16[2]) + b2f(pa16[2]); a.w += b2f(qa16[3]) + b2f(pa16[3]);
    c.x += b2f(qc16[0]) + b2f(pc16[0]); c.y += b2f(qc16[1]) + b2f(pc16[1]);
    c.z += b2f(qc16[2]) + b2f(pc16[2]); c.w += b2f(qc16[3]) + b2f(pc16[3]);
    float s = a.x + a.y + a.z + a.w + c.x + c.y + c.z + c.w;
    float sq = a.x*a.x + a.y*a.y + a.z*a.z + a.w*a.w + c.x*c.x + c.y*c.y + c.z*c.z + c.w*c.w;
    #pragma unroll
    for (int m = 1; m < 64; m <<= 1) { s += __shfl_xor(s, m); sq += __shfl_xor(sq, m); }
    float mean = s * 0.001953125f;
    float var = sq * 0.001953125f - mean * mean;
    float rstd = rsqrtf(var + 1e-5f);
    float4 g0 = *(const float4*)(g + ln * 4);
    float4 g1 = *(const float4*)(g + 256 + ln * 4);
    float4 b0 = *(const float4*)(bta + ln * 4);
    float4 b1 = *(const float4*)(bta + 256 + ln * 4);
    float4 o0, o1;
    o0.x = (a.x - mean) * rstd * g0.x + b0.x;
    o0.y = (a.y - mean) * rstd * g0.y + b0.y;
    o0.z = (a.z - mean) * rstd * g0.z + b0.z;
    o0.w = (a.w - mean) * rstd * g0.w + b0.w;
    o1.x = (c.x - mean) * rstd * g1.x + b1.x;
    o1.y = (c.y - mean) * rstd * g1.y + b1.y;
    o1.z = (c.z - mean) * rstd * g1.z + b1.z;
    o1.w = (c.w - mean) * rstd * g1.w + b1.w;
    *(float4*)(xout + (size_t)row * 512 + ln * 4) = o0;
    *(float4*)(xout + (size_t)row * 512 + 256 + ln * 4) = o1;
    u16 t0[4] = {f2b(o0.x), f2b(o0.y), f2b(o0.z), f2b(o0.w)};
    u16 t1[4] = {f2b(o1.x), f2b(o1.y), f2b(o1.z), f2b(o1.w)};
    *(uint2*)(xbf + (size_t)row * 512 + ln * 4) = *(const uint2*)t0;
    *(uint2*)(xbf + (size_t)row * 512 + 256 + ln * 4) = *(const uint2*)t1;
}

// ---------- final LN -> gelu -> * mark -> bf16 ----------
__global__ __launch_bounds__(256)
void lngelu_kernel(const float* __restrict__ xin, const float* __restrict__ g,
                   const float* __restrict__ bta, const float* __restrict__ mark,
                   u16* __restrict__ outb) {
    const int row = blockIdx.x * 4 + (threadIdx.x >> 6);
    const int ln = threadIdx.x & 63;
    const float* xr = xin + (size_t)row * 512;
    float4 a = *(const float4*)(xr + ln * 4);
    float4 c = *(const float4*)(xr + 256 + ln * 4);
    float s = a.x + a.y + a.z + a.w + c.x + c.y + c.z + c.w;
    float sq = a.x*a.x + a.y*a.y + a.z*a.z + a.w*a.w + c.x*c.x + c.y*c.y + c.z*c.z + c.w*c.w;
    #pragma unroll
    for (int m = 1; m < 64; m <<= 1) { s += __shfl_xor(s, m); sq += __shfl_xor(sq, m); }
    float mean = s * 0.001953125f;
    float var = sq * 0.001953125f - mean * mean;
    float rstd = rsqrtf(var + 1e-5f);
    float mk = mark[row];
    float4 g0 = *(const float4*)(g + ln * 4);
    float4 g1 = *(const float4*)(g + 256 + ln * 4);
    float4 b0 = *(const float4*)(bta + ln * 4);
    float4 b1 = *(const float4*)(bta + 256 + ln * 4);
    float v0 = gelu_exact((a.x - mean) * rstd * g0.x + b0.x) * mk;
    float v1 = gelu_exact((a.y - mean) * rstd * g0.y + b0.y) * mk;
    float v2 = gelu_exact((a.z - mean) * rstd * g0.z + b0.z) * mk;
    float v3 = gelu_exact((a.w - mean) * rstd * g0.w + b0.w) * mk;
    float v4 = gelu_exact((c.x - mean) * rstd * g1.x + b1.x) * mk;
    float v5 = gelu_exact((c.y - mean) * rstd * g1.y + b1.y) * mk;
    float v6 = gelu_exact((c.z - mean) * rstd * g1.z + b1.z) * mk;
    float v7 = gelu_exact((c.w - mean) * rstd * g1.w + b1.w) * mk;
    u16 t0[4] = {f2b(v0), f2b(v1), f2b(v2), f2b(v3)};
    u16 t1[4] = {f2b(v4), f2b(v5), f2b(v6), f2b(v7)};
    *(uint2*)(outb + (size_t)row * 512 + ln * 4) = *(const uint2*)t0;
    *(uint2*)(outb + (size_t)row * 512 + 256 + ln * 4) = *(const uint2*)t1;
}

// ---------- final projection: out[32,10] = gb[32,262144] @ pw[10,262144]^T + pb ----------
__global__ __launch_bounds__(256)
void fproj_kernel(const u16* __restrict__ gb, const u16* __restrict__ pw,
                  const float* __restrict__ pb, float* __restrict__ out) {
    __shared__ float red[32][4];
    int n = blockIdx.x, ks = blockIdx.y, tid = threadIdx.x;
    float acc[32];
    #pragma unroll
    for (int m = 0; m < 32; ++m) acc[m] = 0.f;
    for (int j = 0; j < 8; ++j) {
        size_t k0 = (size_t)ks * 16384 + j * 2048 + tid * 8;
        bf16x8 w8 = *(const bf16x8*)(pw + (size_t)n * 262144 + k0);
        float wf[8];
        #pragma unroll
        for (int e = 0; e < 8; ++e) wf[e] = b2f((u16)w8[e]);
        #pragma unroll
        for (int m = 0; m < 32; ++m) {
            bf16x8 g8 = *(const bf16x8*)(gb + (size_t)m * 262144 + k0);
            float a = acc[m];
            #pragma unroll
            for (int e = 0; e < 8; ++e) a += b2f((u16)g8[e]) * wf[e];
            acc[m] = a;
        }
    }
    int w = tid >> 6;
    #pragma unroll
    for (int m = 0; m < 32; ++m) {
        float s = acc[m];
        s += __shfl_xor(s, 1);  s += __shfl_xor(s, 2);  s += __shfl_xor(s, 4);
        s += __shfl_xor(s, 8);  s += __shfl_xor(s, 16); s += __shfl_xor(s, 32);
        if ((tid & 63) == 0) red[m][w] = s;
    }
    __syncthreads();
    if (tid < 32) {
        int m = tid;
        float s = red[m][0] + red[m][1] + red[m][2] + red[m][3];
        if (ks == 0) s += pb[n];
        atomicAdd(&out[m * 10 + n], s);
    }
}

// =================== host ===================
extern "C" void kernel_launch(void* const* d_in, const int* in_sizes, int n_in,
                              void* d_out, int out_size, void* d_ws, size_t ws_size,
                              hipStream_t stream) {
    const float* x_enc  = (const float*)d_in[0];
    const float* x_mark = (const float*)d_in[1];
    const float* tok_w  = (const float*)d_in[2];
    const float* Wq = (const float*)d_in[3];   const float* bq = (const float*)d_in[4];
    const float* Wk = (const float*)d_in[5];   const float* bk = (const float*)d_in[6];
    const float* Wv = (const float*)d_in[7];   const float* bv = (const float*)d_in[8];
    const float* Wo = (const float*)d_in[9];   const float* bo = (const float*)d_in[10];
    const float* W1 = (const float*)d_in[11];  const float* b1 = (const float*)d_in[12];
    const float* W2 = (const float*)d_in[13];  const float* b2 = (const float*)d_in[14];
    const float* ln1_g = (const float*)d_in[15]; const float* ln1_b = (const float*)d_in[16];
    const float* ln2_g = (const float*)d_in[17]; const float* ln2_b = (const float*)d_in[18];
    const float* norm_g = (const float*)d_in[19]; const float* norm_b = (const float*)d_in[20];
    const float* proj_w = (const float*)d_in[21]; const float* proj_b = (const float*)d_in[22];
    const float* tau_cw = (const float*)d_in[23];
    const float* tau_w0 = (const float*)d_in[24]; const float* tau_b0 = (const float*)d_in[25];
    const float* tau_w1 = (const float*)d_in[26]; const float* tau_b1 = (const float*)d_in[27];
    const float* tau_w2 = (const float*)d_in[28];
    const float* del_cw = (const float*)d_in[29];
    const float* del_w0 = (const float*)d_in[30]; const float* del_b0 = (const float*)d_in[31];
    const float* del_w1 = (const float*)d_in[32]; const float* del_b1 = (const float*)d_in[33];
    const float* del_w2 = (const float*)d_in[34];
    float* out = (float*)d_out;

    char* ws = (char*)d_ws;
    size_t off = 0;
    auto alloc = [&](size_t bytes) -> void* {
        void* p = ws + off;
        off += (bytes + 255) & ~(size_t)255;
        return p;
    };
    u16* wqkvb = (u16*)alloc((size_t)3 * 786432 * 2);   // per layer [1536][512]
    u16* wob = (u16*)alloc(786432 * 2);
    u16* w1b = (u16*)alloc(3145728 * 2);
    u16* w2b = (u16*)alloc(3145728 * 2);
    u16* pwb = (u16*)alloc(2621440 * 2);
    float* bqkvb = (float*)alloc(3 * 1536 * 4);
    float* petab = (float*)alloc((size_t)262144 * 4);
    float* meanb = (float*)alloc(512 * 4);
    float* stdb  = (float*)alloc(512 * 4);
    float* taub  = (float*)alloc(32 * 4);
    float* delb  = (float*)alloc(16384 * 4);
    float* xf = (float*)alloc((size_t)8388608 * 4);
    u16*  xb  = (u16*)alloc((size_t)8388608 * 2);
    u16*  sfb = (u16*)alloc((size_t)8388608 * 2);       // GEMM kz0 output (bf16)
    u16* qkvb = (u16*)alloc((size_t)16384 * 1536 * 2);  // 50.3MB
    u16* ob   = (u16*)alloc((size_t)8388608 * 2);       // 16.8MB
    u16* hb   = qkvb;   // FFN hidden (64MB) overlays qkvb AND first 13.7MB of ob
    u16* gbuf = qkvb;   // final gelu buffer overlays too
    u16* p1o  = qkvb;   // Oproj split-K partial: qkvb dead during Oproj/ln1
    u16* p1f  = xb;     // FFN2 split-K partial: xb dead during FFN2 (see R4 postmortem)

    cvtqkv_kernel<<<dim3(1152), dim3(256), 0, stream>>>(Wq, Wk, Wv, wqkvb);
    cvt4_kernel<<<dim3(5030), dim3(256), 0, stream>>>(Wo, W1, W2, proj_w, wob, w1b, w2b, pwb);
    packb_kernel<<<dim3(18), dim3(256), 0, stream>>>(bq, bk, bv, bqkvb);
    pe_kernel<<<dim3(512), dim3(256), 0, stream>>>(petab);

    stats_kernel<<<dim3(32), dim3(64), 0, stream>>>(x_enc, meanb, stdb);
    proj_kernel<<<dim3(32), dim3(128), 0, stream>>>(x_enc, stdb, tau_cw, tau_w0, tau_b0,
                                                    tau_w1, tau_b1, tau_w2, taub, 1, 1);
    proj_kernel<<<dim3(32), dim3(128), 0, stream>>>(x_enc, meanb, del_cw, del_w0, del_b0,
                                                    del_w1, del_b1, del_w2, delb, 512, 0);
    tokconv_kernel<<<dim3(16, 32), dim3(256), 0, stream>>>(x_enc, tok_w, petab, xf, xb);

    for (int i = 0; i < 3; ++i) {
        const u16* wqkv_i = wqkvb + (size_t)i * 786432;
        const u16* wo_i = wob + (size_t)i * 262144;
        const u16* w1_i = w1b + (size_t)i * 1048576;
        const u16* w2_i = w2b + (size_t)i * 1048576;
        gemm32<0><<<dim3(12, 128, 1), dim3(256), 0, stream>>>(
            xb, wqkv_i, bqkvb + i * 1536, qkvb, nullptr, 16384, 1536, 512, 512);
        attn2_kernel<<<dim3(2, 8, 32), dim3(512), 0, stream>>>(qkvb, taub, delb, ob);
        gemm32<0><<<dim3(4, 128, 2), dim3(256), 0, stream>>>(
            ob, wo_i, bo + i * 512, sfb, p1o, 16384, 512, 512, 256);
        ln3_kernel<<<dim3(4096), dim3(256), 0, stream>>>(xf, sfb, p1o,
            ln1_g + i * 512, ln1_b + i * 512, xf, xb);
        gemm32<1><<<dim3(16, 128, 1), dim3(256), 0, stream>>>(
            xb, w1_i, b1 + i * 2048, hb, nullptr, 16384, 2048, 512, 512);
        gemm32<0><<<dim3(4, 128, 2), dim3(256), 0, stream>>>(
            hb, w2_i, b2 + i * 512, sfb, p1f, 16384, 512, 2048, 1024);
        ln3_kernel<<<dim3(4096), dim3(256), 0, stream>>>(xf, sfb, p1f,
            ln2_g + i * 512, ln2_b + i * 512, xf, xb);
    }

    lngelu_kernel<<<dim3(4096), dim3(256), 0, stream>>>(xf, norm_g, norm_b, x_mark, gbuf);
    hipMemsetAsync(d_out, 0, (size_t)out_size * 4, stream);
    fproj_kernel<<<dim3(10, 16), dim3(256), 0, stream>>>(gbuf, pwb, proj_b, out);
}